// Round 1
// baseline (675.047 us; speedup 1.0000x reference)
//
#include <hip/hip_runtime.h>

// GIN layer: agg = segment_sum(x[col], row); h = (1+eps)*x + agg;
// h = h@W1.T + b1; BN(train) ; ReLU ; out = h@W2.T + b2
// N=100000, E=1600000, F=128. All fp32.

#define F 128

// ---------- K0: transpose W1,W2 into ws (once per launch, tiny) ----------
__global__ void transpose_w_kernel(const float* __restrict__ W1, const float* __restrict__ W2,
                                   float* __restrict__ w1t, float* __restrict__ w2t) {
    int idx = blockIdx.x * 256 + threadIdx.x;   // 16384 threads
    int k = idx >> 7, c = idx & 127;
    w1t[idx] = W1[c * F + k];
    w2t[idx] = W2[c * F + k];
}

// ---------- K1: degree histogram ----------
__global__ void deg_kernel(const int* __restrict__ rows, int* __restrict__ deg, int E) {
    int t = blockIdx.x * blockDim.x + threadIdx.x;
    if (t < E) atomicAdd(&deg[rows[t]], 1);
}

// ---------- K2a: per-chunk sums (chunk = 1024) ----------
__global__ void chunk_sum_kernel(const int* __restrict__ deg, int* __restrict__ blockSums, int n) {
    int b = blockIdx.x, t = threadIdx.x;
    int base = b * 1024 + t * 4;
    int s = 0;
#pragma unroll
    for (int j = 0; j < 4; j++) { int i = base + j; if (i < n) s += deg[i]; }
    for (int off = 32; off > 0; off >>= 1) s += __shfl_down(s, off, 64);
    __shared__ int wsum[4];
    int wave = t >> 6, lane = t & 63;
    if (lane == 0) wsum[wave] = s;
    __syncthreads();
    if (t == 0) blockSums[b] = wsum[0] + wsum[1] + wsum[2] + wsum[3];
}

// ---------- K2b: scan the (<=128) chunk sums, write grand total ----------
__global__ void scan_block_sums_kernel(const int* __restrict__ blockSums, int* __restrict__ blockOffsets,
                                       int* __restrict__ totalOut, int nb) {
    __shared__ int tmp[128];
    int t = threadIdx.x;
    int v = (t < nb) ? blockSums[t] : 0;
    tmp[t] = v;
    __syncthreads();
    for (int off = 1; off < 128; off <<= 1) {
        int u = (t >= off) ? tmp[t - off] : 0;
        __syncthreads();
        tmp[t] += u;
        __syncthreads();
    }
    if (t < nb) blockOffsets[t] = tmp[t] - v;
    if (t == 127) *totalOut = tmp[127];
}

// ---------- K2c: in-place exclusive scan within each chunk (+copy to cursor) ----------
__global__ void scan_within_kernel(int* __restrict__ offs, int* __restrict__ cursor,
                                   const int* __restrict__ blockOffsets, int n) {
    int b = blockIdx.x, t = threadIdx.x;
    int base = b * 1024 + t * 4;
    int v[4];
#pragma unroll
    for (int j = 0; j < 4; j++) { int i = base + j; v[j] = (i < n) ? offs[i] : 0; }
    int tot = v[0] + v[1] + v[2] + v[3];
    __shared__ int tmp[256];
    tmp[t] = tot;
    __syncthreads();
    for (int off = 1; off < 256; off <<= 1) {
        int u = (t >= off) ? tmp[t - off] : 0;
        __syncthreads();
        tmp[t] += u;
        __syncthreads();
    }
    int run = tmp[t] - tot + blockOffsets[b];
#pragma unroll
    for (int j = 0; j < 4; j++) {
        int i = base + j;
        if (i < n) { offs[i] = run; cursor[i] = run; }
        run += v[j];
    }
}

// ---------- K3: scatter edges into CSR ----------
__global__ void scatter_kernel(const int* __restrict__ rows, const int* __restrict__ cols,
                               int* __restrict__ cursor, int* __restrict__ colSorted, int E) {
    int t = blockIdx.x * blockDim.x + threadIdx.x;
    if (t < E) {
        int r = rows[t];
        int p = atomicAdd(&cursor[r], 1);
        colSorted[p] = cols[t];
    }
}

// ---------- K4: per-node gather-aggregate: h0 = (1+eps)*x + sum_neighbors x ----------
__global__ __launch_bounds__(256) void agg_kernel(const float* __restrict__ x, const int* __restrict__ offs,
                                                  const int* __restrict__ colSorted, const float* __restrict__ epsPtr,
                                                  float* __restrict__ h0, int n) {
    int wave = threadIdx.x >> 6, lane = threadIdx.x & 63;
    int node = blockIdx.x * 4 + wave;
    if (node >= n) return;
    float sc = 1.0f + epsPtr[0];
    float2 acc = ((const float2*)(x + (size_t)node * F))[lane];
    acc.x *= sc; acc.y *= sc;
    int s = offs[node], e = offs[node + 1];
    int i = s;
    for (; i + 4 <= e; i += 4) {
        int c0 = colSorted[i], c1 = colSorted[i + 1], c2 = colSorted[i + 2], c3 = colSorted[i + 3];
        float2 v0 = ((const float2*)(x + (size_t)c0 * F))[lane];
        float2 v1 = ((const float2*)(x + (size_t)c1 * F))[lane];
        float2 v2 = ((const float2*)(x + (size_t)c2 * F))[lane];
        float2 v3 = ((const float2*)(x + (size_t)c3 * F))[lane];
        acc.x += (v0.x + v1.x) + (v2.x + v3.x);
        acc.y += (v0.y + v1.y) + (v2.y + v3.y);
    }
    for (; i < e; ++i) {
        int c = colSorted[i];
        float2 v = ((const float2*)(x + (size_t)c * F))[lane];
        acc.x += v.x; acc.y += v.y;
    }
    ((float2*)(h0 + (size_t)node * F))[lane] = acc;
}

// ---------- K5: GEMM1 (h0 @ W1^T + b1) + BN partial stats ----------
// block=256 (4 waves); wave handles 8 rows; lane handles cols (2l, 2l+1).
__global__ __launch_bounds__(256, 2) void gemm1_stats_kernel(const float* __restrict__ h0, const float* __restrict__ w1t,
                                                             const float* __restrict__ b1, float* __restrict__ h1,
                                                             float* __restrict__ stats, int n) {
    __shared__ float wl[F * F];   // 64KB: wl[k*128+c] = W1[c][k]
    {
        const float4* src = (const float4*)w1t;
        float4* dst = (float4*)wl;
        for (int i = threadIdx.x; i < F * F / 4; i += 256) dst[i] = src[i];
    }
    __syncthreads();
    int wave = threadIdx.x >> 6, lane = threadIdx.x & 63;
    int c0 = lane * 2;
    float bb0 = b1[c0], bb1 = b1[c0 + 1];
    float sum0 = 0, sum1 = 0, sq0 = 0, sq1 = 0;
    int numTiles = (n + 31) / 32;
    for (int tile = blockIdx.x; tile < numTiles; tile += gridDim.x) {
        int rbase = tile * 32 + wave * 8;
        const float* rp[8];
#pragma unroll
        for (int j = 0; j < 8; j++) { int r = rbase + j; rp[j] = h0 + (size_t)(r < n ? r : 0) * F; }
        float acc[8][2];
#pragma unroll
        for (int j = 0; j < 8; j++) { acc[j][0] = bb0; acc[j][1] = bb1; }
        for (int k4 = 0; k4 < F; k4 += 4) {
            float4 xv[8];
#pragma unroll
            for (int j = 0; j < 8; j++) xv[j] = *(const float4*)(rp[j] + k4);
#pragma unroll
            for (int kk = 0; kk < 4; kk++) {
                float2 wv = *(const float2*)&wl[(k4 + kk) * F + c0];
#pragma unroll
                for (int j = 0; j < 8; j++) {
                    float xk = ((const float*)&xv[j])[kk];
                    acc[j][0] = fmaf(xk, wv.x, acc[j][0]);
                    acc[j][1] = fmaf(xk, wv.y, acc[j][1]);
                }
            }
        }
#pragma unroll
        for (int j = 0; j < 8; j++) {
            int r = rbase + j;
            if (r < n) {
                float a0 = acc[j][0], a1 = acc[j][1];
                ((float2*)(h1 + (size_t)r * F))[lane] = make_float2(a0, a1);
                sum0 += a0; sum1 += a1; sq0 += a0 * a0; sq1 += a1 * a1;
            }
        }
    }
    // block-level stats reduce (reuse wl), then one atomic set per block
    __syncthreads();
    wl[wave * F + c0] = sum0; wl[wave * F + c0 + 1] = sum1;
    wl[512 + wave * F + c0] = sq0; wl[512 + wave * F + c0 + 1] = sq1;
    __syncthreads();
    if (wave == 0) {
        float S0 = 0, S1 = 0, Q0 = 0, Q1 = 0;
#pragma unroll
        for (int w = 0; w < 4; w++) {
            S0 += wl[w * F + c0]; S1 += wl[w * F + c0 + 1];
            Q0 += wl[512 + w * F + c0]; Q1 += wl[512 + w * F + c0 + 1];
        }
        atomicAdd(&stats[c0], S0); atomicAdd(&stats[c0 + 1], S1);
        atomicAdd(&stats[F + c0], Q0); atomicAdd(&stats[F + c0 + 1], Q1);
    }
}

// ---------- K6: finalize BN -> scale/shift ----------
__global__ void bn_finalize_kernel(const float* __restrict__ stats, const float* __restrict__ gamma,
                                   const float* __restrict__ beta, float* __restrict__ ss, int n) {
    int c = threadIdx.x;
    float inv_n = 1.0f / (float)n;
    float mu = stats[c] * inv_n;
    float var = stats[F + c] * inv_n - mu * mu;
    var = fmaxf(var, 0.0f);
    float rs = rsqrtf(var + 1e-5f);
    float s = gamma[c] * rs;
    ss[c] = s;
    ss[F + c] = beta[c] - mu * s;
}

// ---------- K7: GEMM2 with fused BN+ReLU on input. h1 and out alias (d_out): ----------
// each row is read & written by the same wave only -> safe (loads precede stores in program order).
__global__ __launch_bounds__(256, 2) void gemm2_kernel(const float* __restrict__ w2t, const float* __restrict__ b2,
                                                       const float* __restrict__ ss, float* hbuf, int n) {
    __shared__ float wl[F * F];
    {
        const float4* src = (const float4*)w2t;
        float4* dst = (float4*)wl;
        for (int i = threadIdx.x; i < F * F / 4; i += 256) dst[i] = src[i];
    }
    __syncthreads();
    int wave = threadIdx.x >> 6, lane = threadIdx.x & 63;
    int c0 = lane * 2;
    float bb0 = b2[c0], bb1 = b2[c0 + 1];
    int numTiles = (n + 31) / 32;
    for (int tile = blockIdx.x; tile < numTiles; tile += gridDim.x) {
        int rbase = tile * 32 + wave * 8;
        float* rp[8];
#pragma unroll
        for (int j = 0; j < 8; j++) { int r = rbase + j; rp[j] = hbuf + (size_t)(r < n ? r : 0) * F; }
        float acc[8][2];
#pragma unroll
        for (int j = 0; j < 8; j++) { acc[j][0] = bb0; acc[j][1] = bb1; }
        for (int k4 = 0; k4 < F; k4 += 4) {
            float4 sv = *(const float4*)(ss + k4);
            float4 tv = *(const float4*)(ss + F + k4);
            float4 xv[8];
#pragma unroll
            for (int j = 0; j < 8; j++) xv[j] = *(const float4*)(rp[j] + k4);
#pragma unroll
            for (int kk = 0; kk < 4; kk++) {
                float2 wv = *(const float2*)&wl[(k4 + kk) * F + c0];
                float skk = ((const float*)&sv)[kk];
                float tkk = ((const float*)&tv)[kk];
#pragma unroll
                for (int j = 0; j < 8; j++) {
                    float xk = ((const float*)&xv[j])[kk];
                    float v = fmaxf(fmaf(xk, skk, tkk), 0.0f);   // BN + ReLU
                    acc[j][0] = fmaf(v, wv.x, acc[j][0]);
                    acc[j][1] = fmaf(v, wv.y, acc[j][1]);
                }
            }
        }
#pragma unroll
        for (int j = 0; j < 8; j++) {
            int r = rbase + j;
            if (r < n) ((float2*)(rp[j]))[lane] = make_float2(acc[j][0], acc[j][1]);
        }
    }
}

extern "C" void kernel_launch(void* const* d_in, const int* in_sizes, int n_in,
                              void* d_out, int out_size, void* d_ws, size_t ws_size,
                              hipStream_t stream) {
    const float* x     = (const float*)d_in[0];
    const int*   ei    = (const int*)d_in[1];
    const float* eps   = (const float*)d_in[2];
    const float* W1    = (const float*)d_in[3];
    const float* b1    = (const float*)d_in[4];
    const float* gamma = (const float*)d_in[5];
    const float* beta  = (const float*)d_in[6];
    const float* W2    = (const float*)d_in[7];
    const float* b2    = (const float*)d_in[8];
    float* out = (float*)d_out;

    const int E = in_sizes[1] / 2;
    const int n = in_sizes[0] / F;

    // bump-allocate workspace (256B aligned); total ~58.6 MB
    char* w = (char*)d_ws;
    auto alloc = [&](size_t bytes) -> void* {
        void* p = (void*)w;
        w += (bytes + 255) & ~(size_t)255;
        return p;
    };
    int*   offs         = (int*)alloc((size_t)(n + 1) * 4);  // degrees -> offsets (in-place scan)
    int*   cursor       = (int*)alloc((size_t)n * 4);
    int*   blockSums    = (int*)alloc(128 * 4);
    int*   blockOffsets = (int*)alloc(128 * 4);
    float* stats        = (float*)alloc(256 * 4);
    float* ss           = (float*)alloc(256 * 4);
    float* w1t          = (float*)alloc(F * F * 4);
    float* w2t          = (float*)alloc(F * F * 4);
    int*   colSorted    = (int*)alloc((size_t)E * 4);
    float* h0           = (float*)alloc((size_t)n * F * 4);

    const int* rows = ei;
    const int* cols = ei + E;

    hipMemsetAsync(offs, 0, (size_t)(n + 1) * 4, stream);
    hipMemsetAsync(stats, 0, 256 * 4, stream);

    transpose_w_kernel<<<64, 256, 0, stream>>>(W1, W2, w1t, w2t);
    deg_kernel<<<(E + 255) / 256, 256, 0, stream>>>(rows, offs, E);
    int nb = (n + 1023) / 1024;
    chunk_sum_kernel<<<nb, 256, 0, stream>>>(offs, blockSums, n);
    scan_block_sums_kernel<<<1, 128, 0, stream>>>(blockSums, blockOffsets, offs + n, nb);
    scan_within_kernel<<<nb, 256, 0, stream>>>(offs, cursor, blockOffsets, n);
    scatter_kernel<<<(E + 255) / 256, 256, 0, stream>>>(rows, cols, cursor, colSorted, E);
    agg_kernel<<<(n + 3) / 4, 256, 0, stream>>>(x, offs, colSorted, eps, h0, n);
    gemm1_stats_kernel<<<1024, 256, 0, stream>>>(h0, w1t, b1, out, stats, n);
    bn_finalize_kernel<<<1, 128, 0, stream>>>(stats, gamma, beta, ss, n);
    gemm2_kernel<<<1024, 256, 0, stream>>>(w2t, b2, ss, out, n);
}

// Round 2
// 567.758 us; speedup vs baseline: 1.1890x; 1.1890x over previous
//
#include <hip/hip_runtime.h>

// GIN layer: agg = segment_sum(x[col], row); h = (1+eps)*x + agg;
// h = h@W1.T + b1; BN(train) ; ReLU ; out = h@W2.T + b2
// N=100000, E=1600000, F=128. All fp32.

#define F 128

// ---------- K0: transpose W1,W2 into ws (once per launch, tiny) ----------
__global__ void transpose_w_kernel(const float* __restrict__ W1, const float* __restrict__ W2,
                                   float* __restrict__ w1t, float* __restrict__ w2t) {
    int idx = blockIdx.x * 256 + threadIdx.x;   // 16384 threads
    int k = idx >> 7, c = idx & 127;
    w1t[idx] = W1[c * F + k];
    w2t[idx] = W2[c * F + k];
}

// ---------- K1: degree histogram ----------
__global__ void deg_kernel(const int* __restrict__ rows, int* __restrict__ deg, int E) {
    int t = blockIdx.x * blockDim.x + threadIdx.x;
    if (t < E) atomicAdd(&deg[rows[t]], 1);
}

// ---------- K2a: per-chunk sums (chunk = 1024) ----------
__global__ void chunk_sum_kernel(const int* __restrict__ deg, int* __restrict__ blockSums, int n) {
    int b = blockIdx.x, t = threadIdx.x;
    int base = b * 1024 + t * 4;
    int s = 0;
#pragma unroll
    for (int j = 0; j < 4; j++) { int i = base + j; if (i < n) s += deg[i]; }
    for (int off = 32; off > 0; off >>= 1) s += __shfl_down(s, off, 64);
    __shared__ int wsum[4];
    int wave = t >> 6, lane = t & 63;
    if (lane == 0) wsum[wave] = s;
    __syncthreads();
    if (t == 0) blockSums[b] = wsum[0] + wsum[1] + wsum[2] + wsum[3];
}

// ---------- K2b: scan the (<=128) chunk sums, write grand total ----------
__global__ void scan_block_sums_kernel(const int* __restrict__ blockSums, int* __restrict__ blockOffsets,
                                       int* __restrict__ totalOut, int nb) {
    __shared__ int tmp[128];
    int t = threadIdx.x;
    int v = (t < nb) ? blockSums[t] : 0;
    tmp[t] = v;
    __syncthreads();
    for (int off = 1; off < 128; off <<= 1) {
        int u = (t >= off) ? tmp[t - off] : 0;
        __syncthreads();
        tmp[t] += u;
        __syncthreads();
    }
    if (t < nb) blockOffsets[t] = tmp[t] - v;
    if (t == 127) *totalOut = tmp[127];
}

// ---------- K2c: in-place exclusive scan within each chunk (+copy to cursor) ----------
__global__ void scan_within_kernel(int* __restrict__ offs, int* __restrict__ cursor,
                                   const int* __restrict__ blockOffsets, int n) {
    int b = blockIdx.x, t = threadIdx.x;
    int base = b * 1024 + t * 4;
    int v[4];
#pragma unroll
    for (int j = 0; j < 4; j++) { int i = base + j; v[j] = (i < n) ? offs[i] : 0; }
    int tot = v[0] + v[1] + v[2] + v[3];
    __shared__ int tmp[256];
    tmp[t] = tot;
    __syncthreads();
    for (int off = 1; off < 256; off <<= 1) {
        int u = (t >= off) ? tmp[t - off] : 0;
        __syncthreads();
        tmp[t] += u;
        __syncthreads();
    }
    int run = tmp[t] - tot + blockOffsets[b];
#pragma unroll
    for (int j = 0; j < 4; j++) {
        int i = base + j;
        if (i < n) { offs[i] = run; cursor[i] = run; }
        run += v[j];
    }
}

// ---------- K3: scatter edges into CSR ----------
__global__ void scatter_kernel(const int* __restrict__ rows, const int* __restrict__ cols,
                               int* __restrict__ cursor, int* __restrict__ colSorted, int E) {
    int t = blockIdx.x * blockDim.x + threadIdx.x;
    if (t < E) {
        int r = rows[t];
        int p = atomicAdd(&cursor[r], 1);
        colSorted[p] = cols[t];
    }
}

// ---------- K4: per-node gather-aggregate: h0 = (1+eps)*x + sum_neighbors x ----------
__global__ __launch_bounds__(256) void agg_kernel(const float* __restrict__ x, const int* __restrict__ offs,
                                                  const int* __restrict__ colSorted, const float* __restrict__ epsPtr,
                                                  float* __restrict__ h0, int n) {
    int wave = threadIdx.x >> 6, lane = threadIdx.x & 63;
    int node = blockIdx.x * 4 + wave;
    if (node >= n) return;
    float sc = 1.0f + epsPtr[0];
    float2 acc = ((const float2*)(x + (size_t)node * F))[lane];
    acc.x *= sc; acc.y *= sc;
    int s = offs[node], e = offs[node + 1];
    int i = s;
    for (; i + 4 <= e; i += 4) {
        int c0 = colSorted[i], c1 = colSorted[i + 1], c2 = colSorted[i + 2], c3 = colSorted[i + 3];
        float2 v0 = ((const float2*)(x + (size_t)c0 * F))[lane];
        float2 v1 = ((const float2*)(x + (size_t)c1 * F))[lane];
        float2 v2 = ((const float2*)(x + (size_t)c2 * F))[lane];
        float2 v3 = ((const float2*)(x + (size_t)c3 * F))[lane];
        acc.x += (v0.x + v1.x) + (v2.x + v3.x);
        acc.y += (v0.y + v1.y) + (v2.y + v3.y);
    }
    for (; i < e; ++i) {
        int c = colSorted[i];
        float2 v = ((const float2*)(x + (size_t)c * F))[lane];
        acc.x += v.x; acc.y += v.y;
    }
    ((float2*)(h0 + (size_t)node * F))[lane] = acc;
}

// ---------- K5: GEMM1 (h0 @ W1^T + b1) + BN partial stats ----------
// Tile = 64 rows staged in LDS (32KB -> 4 blocks/CU with launch_bounds(256,4)).
// Weights read from global (64KB, L2-resident, coalesced float2 per lane).
// Wave handles 16 rows; lane handles cols (2l, 2l+1). x read from LDS (broadcast = free).
__global__ __launch_bounds__(256, 4) void gemm1_stats_kernel(const float* __restrict__ h0,
                                                             const float* __restrict__ wt,
                                                             const float* __restrict__ b1,
                                                             float* __restrict__ h1,
                                                             float* __restrict__ stats, int n) {
    __shared__ float xs[64 * F];   // 32KB x-tile
    int tid = threadIdx.x;
    int tb = blockIdx.x * 64;
    // ---- stage 64 rows, coalesced float4, lane-distinct ----
    float4* xs4 = (float4*)xs;
#pragma unroll
    for (int j = 0; j < 8; j++) {
        int idx = tid + 256 * j;            // 0..2047
        int row = idx >> 5;                 // 0..63
        int g = tb + row; if (g >= n) g = n - 1;
        xs4[idx] = ((const float4*)(h0 + (size_t)g * F))[idx & 31];
    }
    __syncthreads();

    int wave = tid >> 6, lane = tid & 63;
    int rb = wave * 16;
    int c0 = lane * 2;
    float2 bb = *(const float2*)(b1 + c0);
    float acc[16][2];
#pragma unroll
    for (int j = 0; j < 16; j++) { acc[j][0] = bb.x; acc[j][1] = bb.y; }

    for (int k4 = 0; k4 < F; k4 += 4) {
        float2 wv[4];
#pragma unroll
        for (int kk = 0; kk < 4; kk++)
            wv[kk] = *(const float2*)(wt + (size_t)(k4 + kk) * F + c0);
#pragma unroll
        for (int half = 0; half < 2; half++) {
            float4 xv[8];
#pragma unroll
            for (int j = 0; j < 8; j++)
                xv[j] = *(const float4*)(xs + (rb + half * 8 + j) * F + k4);
#pragma unroll
            for (int kk = 0; kk < 4; kk++) {
#pragma unroll
                for (int j = 0; j < 8; j++) {
                    float xk = ((const float*)&xv[j])[kk];
                    int r = half * 8 + j;
                    acc[r][0] = fmaf(xk, wv[kk].x, acc[r][0]);
                    acc[r][1] = fmaf(xk, wv[kk].y, acc[r][1]);
                }
            }
        }
    }

    float sum0 = 0, sum1 = 0, sq0 = 0, sq1 = 0;
#pragma unroll
    for (int j = 0; j < 16; j++) {
        int r = tb + rb + j;
        if (r < n) {
            float a0 = acc[j][0], a1 = acc[j][1];
            ((float2*)(h1 + (size_t)r * F))[lane] = make_float2(a0, a1);
            sum0 += a0; sum1 += a1; sq0 += a0 * a0; sq1 += a1 * a1;
        }
    }
    // block-level stats reduce in (now-free) xs, one atomic pair per col per block
    __syncthreads();
    xs[wave * F + c0] = sum0; xs[wave * F + c0 + 1] = sum1;
    xs[512 + wave * F + c0] = sq0; xs[512 + wave * F + c0 + 1] = sq1;
    __syncthreads();
    if (wave == 0) {
        float S0 = 0, S1 = 0, Q0 = 0, Q1 = 0;
#pragma unroll
        for (int w = 0; w < 4; w++) {
            S0 += xs[w * F + c0]; S1 += xs[w * F + c0 + 1];
            Q0 += xs[512 + w * F + c0]; Q1 += xs[512 + w * F + c0 + 1];
        }
        atomicAdd(&stats[c0], S0); atomicAdd(&stats[c0 + 1], S1);
        atomicAdd(&stats[F + c0], Q0); atomicAdd(&stats[F + c0 + 1], Q1);
    }
}

// ---------- K6: finalize BN -> scale/shift ----------
__global__ void bn_finalize_kernel(const float* __restrict__ stats, const float* __restrict__ gamma,
                                   const float* __restrict__ beta, float* __restrict__ ss, int n) {
    int c = threadIdx.x;
    float inv_n = 1.0f / (float)n;
    float mu = stats[c] * inv_n;
    float var = stats[F + c] * inv_n - mu * mu;
    var = fmaxf(var, 0.0f);
    float rs = rsqrtf(var + 1e-5f);
    float s = gamma[c] * rs;
    ss[c] = s;
    ss[F + c] = beta[c] - mu * s;
}

// ---------- K7: GEMM2, BN+ReLU fused into the LDS staging ----------
// In-place on hbuf (=d_out): each block reads & writes only its own 64 rows.
__global__ __launch_bounds__(256, 4) void gemm2_kernel(const float* __restrict__ wt,
                                                       const float* __restrict__ b2,
                                                       const float* __restrict__ ss,
                                                       float* hbuf, int n) {
    __shared__ float xs[64 * F];
    int tid = threadIdx.x;
    int tb = blockIdx.x * 64;
    int kg = tid & 31;                       // this thread's fixed k-group
    float4 sv = *(const float4*)(ss + kg * 4);
    float4 tv = *(const float4*)(ss + F + kg * 4);
    float4* xs4 = (float4*)xs;
#pragma unroll
    for (int j = 0; j < 8; j++) {
        int idx = tid + 256 * j;
        int row = idx >> 5;
        int g = tb + row; if (g >= n) g = n - 1;
        float4 v = ((const float4*)(hbuf + (size_t)g * F))[idx & 31];
        v.x = fmaxf(fmaf(v.x, sv.x, tv.x), 0.0f);
        v.y = fmaxf(fmaf(v.y, sv.y, tv.y), 0.0f);
        v.z = fmaxf(fmaf(v.z, sv.z, tv.z), 0.0f);
        v.w = fmaxf(fmaf(v.w, sv.w, tv.w), 0.0f);
        xs4[idx] = v;
    }
    __syncthreads();

    int wave = tid >> 6, lane = tid & 63;
    int rb = wave * 16;
    int c0 = lane * 2;
    float2 bb = *(const float2*)(b2 + c0);
    float acc[16][2];
#pragma unroll
    for (int j = 0; j < 16; j++) { acc[j][0] = bb.x; acc[j][1] = bb.y; }

    for (int k4 = 0; k4 < F; k4 += 4) {
        float2 wv[4];
#pragma unroll
        for (int kk = 0; kk < 4; kk++)
            wv[kk] = *(const float2*)(wt + (size_t)(k4 + kk) * F + c0);
#pragma unroll
        for (int half = 0; half < 2; half++) {
            float4 xv[8];
#pragma unroll
            for (int j = 0; j < 8; j++)
                xv[j] = *(const float4*)(xs + (rb + half * 8 + j) * F + k4);
#pragma unroll
            for (int kk = 0; kk < 4; kk++) {
#pragma unroll
                for (int j = 0; j < 8; j++) {
                    float xk = ((const float*)&xv[j])[kk];
                    int r = half * 8 + j;
                    acc[r][0] = fmaf(xk, wv[kk].x, acc[r][0]);
                    acc[r][1] = fmaf(xk, wv[kk].y, acc[r][1]);
                }
            }
        }
    }
#pragma unroll
    for (int j = 0; j < 16; j++) {
        int r = tb + rb + j;
        if (r < n)
            ((float2*)(hbuf + (size_t)r * F))[lane] = make_float2(acc[j][0], acc[j][1]);
    }
}

extern "C" void kernel_launch(void* const* d_in, const int* in_sizes, int n_in,
                              void* d_out, int out_size, void* d_ws, size_t ws_size,
                              hipStream_t stream) {
    const float* x     = (const float*)d_in[0];
    const int*   ei    = (const int*)d_in[1];
    const float* eps   = (const float*)d_in[2];
    const float* W1    = (const float*)d_in[3];
    const float* b1    = (const float*)d_in[4];
    const float* gamma = (const float*)d_in[5];
    const float* beta  = (const float*)d_in[6];
    const float* W2    = (const float*)d_in[7];
    const float* b2    = (const float*)d_in[8];
    float* out = (float*)d_out;

    const int E = in_sizes[1] / 2;
    const int n = in_sizes[0] / F;

    // bump-allocate workspace (256B aligned)
    char* w = (char*)d_ws;
    auto alloc = [&](size_t bytes) -> void* {
        void* p = (void*)w;
        w += (bytes + 255) & ~(size_t)255;
        return p;
    };
    int*   offs         = (int*)alloc((size_t)(n + 1) * 4);
    int*   cursor       = (int*)alloc((size_t)n * 4);
    int*   blockSums    = (int*)alloc(128 * 4);
    int*   blockOffsets = (int*)alloc(128 * 4);
    float* stats        = (float*)alloc(256 * 4);
    float* ss           = (float*)alloc(256 * 4);
    float* w1t          = (float*)alloc(F * F * 4);
    float* w2t          = (float*)alloc(F * F * 4);
    int*   colSorted    = (int*)alloc((size_t)E * 4);
    float* h0           = (float*)alloc((size_t)n * F * 4);

    const int* rows = ei;
    const int* cols = ei + E;

    hipMemsetAsync(offs, 0, (size_t)(n + 1) * 4, stream);
    hipMemsetAsync(stats, 0, 256 * 4, stream);

    transpose_w_kernel<<<64, 256, 0, stream>>>(W1, W2, w1t, w2t);
    deg_kernel<<<(E + 255) / 256, 256, 0, stream>>>(rows, offs, E);
    int nb = (n + 1023) / 1024;
    chunk_sum_kernel<<<nb, 256, 0, stream>>>(offs, blockSums, n);
    scan_block_sums_kernel<<<1, 128, 0, stream>>>(blockSums, blockOffsets, offs + n, nb);
    scan_within_kernel<<<nb, 256, 0, stream>>>(offs, cursor, blockOffsets, n);
    scatter_kernel<<<(E + 255) / 256, 256, 0, stream>>>(rows, cols, cursor, colSorted, E);
    agg_kernel<<<(n + 3) / 4, 256, 0, stream>>>(x, offs, colSorted, eps, h0, n);

    int ntiles = (n + 63) / 64;
    gemm1_stats_kernel<<<ntiles, 256, 0, stream>>>(h0, w1t, b1, out, stats, n);
    bn_finalize_kernel<<<1, 128, 0, stream>>>(stats, gamma, beta, ss, n);
    gemm2_kernel<<<ntiles, 256, 0, stream>>>(w2t, b2, ss, out, n);
}

// Round 3
// 450.936 us; speedup vs baseline: 1.4970x; 1.2591x over previous
//
#include <hip/hip_runtime.h>

// GIN layer: agg = segment_sum(x[col], row); h = (1+eps)*x + agg;
// h = h@W1.T + b1; BN(train) ; ReLU ; out = h@W2.T + b2
// N=100000, E=1600000, F=128. All fp32.

#define F 128
#define NPB 64          // nodes per bucket
#define CAP 2048        // LDS record capacity per chunk (avg bucket = 1024 edges)

// ---------- K0: transpose W1,W2 into ws ----------
__global__ void transpose_w_kernel(const float* __restrict__ W1, const float* __restrict__ W2,
                                   float* __restrict__ w1t, float* __restrict__ w2t) {
    int idx = blockIdx.x * 256 + threadIdx.x;   // 16384 threads
    int k = idx >> 7, c = idx & 127;
    w1t[idx] = W1[c * F + k];
    w2t[idx] = W2[c * F + k];
}

// ---------- K1: bucket histogram (LDS-aggregated) ----------
__global__ __launch_bounds__(256) void bucket_hist_kernel(const int* __restrict__ rows,
                                                          int* __restrict__ bucketCnt,
                                                          int E, int nbuk) {
    extern __shared__ int bh[];     // nbuk ints
    int tid = threadIdx.x;
    for (int i = tid; i < nbuk; i += 256) bh[i] = 0;
    __syncthreads();
    int stride = gridDim.x * 256;
    for (int i = blockIdx.x * 256 + tid; i < E; i += stride)
        atomicAdd(&bh[rows[i] >> 6], 1);
    __syncthreads();
    for (int b = tid; b < nbuk; b += 256) {
        int c = bh[b];
        if (c) atomicAdd(&bucketCnt[b], c);
    }
}

// ---------- K2: exclusive scan of bucket counts -> offsets + cursor ----------
__global__ void scan_buckets_kernel(const int* __restrict__ bucketCnt, int* __restrict__ bOffs,
                                    int* __restrict__ gcursor, int nbuk) {
    const int SEG = 7;   // 256*7 = 1792 >= 1563
    __shared__ int tmp[256];
    int t = threadIdx.x;
    int base = t * SEG;
    int v[SEG], s = 0;
#pragma unroll
    for (int j = 0; j < SEG; j++) {
        int idx = base + j;
        v[j] = (idx < nbuk) ? bucketCnt[idx] : 0;
        s += v[j];
    }
    tmp[t] = s;
    __syncthreads();
    for (int off = 1; off < 256; off <<= 1) {
        int u = (t >= off) ? tmp[t - off] : 0;
        __syncthreads();
        tmp[t] += u;
        __syncthreads();
    }
    int run = tmp[t] - s;
#pragma unroll
    for (int j = 0; j < SEG; j++) {
        int idx = base + j;
        if (idx < nbuk) { bOffs[idx] = run; gcursor[idx] = run; }
        run += v[j];
    }
    if (t == 255) bOffs[nbuk] = tmp[255];
}

// ---------- K3: binned scatter: records (col<<6 | row&63) grouped by bucket ----------
__global__ __launch_bounds__(1024) void binned_scatter_kernel(const int* __restrict__ rows,
                                                              const int* __restrict__ cols,
                                                              int* __restrict__ gcursor,
                                                              int* __restrict__ recbuf,
                                                              int E, int nbuk) {
    extern __shared__ int sm[];     // bh[nbuk], gb[nbuk]
    int* bh = sm;
    int* gb = sm + nbuk;
    int tid = threadIdx.x;
    int chunk = (E + gridDim.x - 1) / gridDim.x;
    int e0 = blockIdx.x * chunk;
    int e1 = min(E, e0 + chunk);
    for (int i = tid; i < nbuk; i += 1024) bh[i] = 0;
    __syncthreads();
    for (int i = e0 + tid; i < e1; i += 1024)
        atomicAdd(&bh[rows[i] >> 6], 1);
    __syncthreads();
    for (int b = tid; b < nbuk; b += 1024) {
        int c = bh[b];
        gb[b] = c ? atomicAdd(&gcursor[b], c) : 0;
        bh[b] = 0;
    }
    __syncthreads();
    for (int i = e0 + tid; i < e1; i += 1024) {
        int r = rows[i], c = cols[i];
        int k = r >> 6;
        int rk = atomicAdd(&bh[k], 1);
        recbuf[gb[k] + rk] = (c << 6) | (r & 63);
    }
}

// ---------- K4: fused mini-CSR build + gather-aggregate ----------
// One block per bucket (64 nodes). Build per-chunk CSR in LDS, gather x rows.
__global__ __launch_bounds__(256) void agg_fused_kernel(const float* __restrict__ x,
                                                        const int* __restrict__ bOffs,
                                                        const int* __restrict__ recbuf,
                                                        const float* __restrict__ epsPtr,
                                                        float* __restrict__ h0, int n) {
    __shared__ int rec[CAP];
    __shared__ int clist[CAP];
    __shared__ int hist[NPB];
    __shared__ int loffs[NPB + 1];
    __shared__ int cur[NPB];
    int tid = threadIdx.x, wave = tid >> 6, lane = tid & 63;
    int nb0 = blockIdx.x * NPB;
    int base = bOffs[blockIdx.x];
    int cnt = bOffs[blockIdx.x + 1] - base;
    float sc = 1.0f + epsPtr[0];

    float2 acc[16];
#pragma unroll
    for (int j = 0; j < 16; j++) {
        int g = nb0 + wave * 16 + j;
        if (g < n) {
            float2 v = ((const float2*)(x + (size_t)g * F))[lane];
            acc[j] = make_float2(v.x * sc, v.y * sc);
        } else acc[j] = make_float2(0.f, 0.f);
    }

    for (int cs = 0; cs < cnt; cs += CAP) {
        int m = min(CAP, cnt - cs);
        for (int i = tid; i < m; i += 256) rec[i] = recbuf[base + cs + i];
        if (tid < NPB) hist[tid] = 0;
        __syncthreads();
        for (int i = tid; i < m; i += 256) atomicAdd(&hist[rec[i] & 63], 1);
        __syncthreads();
        if (tid < 64) {
            int h = hist[tid], v = h;
#pragma unroll
            for (int off = 1; off < 64; off <<= 1) {
                int u = __shfl_up(v, off, 64);
                if (tid >= off) v += u;
            }
            loffs[tid + 1] = v;
            if (tid == 0) loffs[0] = 0;
            cur[tid] = v - h;
        }
        __syncthreads();
        for (int i = tid; i < m; i += 256) {
            int r = rec[i];
            int p = atomicAdd(&cur[r & 63], 1);
            clist[p] = r >> 6;
        }
        __syncthreads();
#pragma unroll
        for (int j = 0; j < 16; j++) {
            int ln = wave * 16 + j;
            int s = loffs[ln], e = loffs[ln + 1];
            int i = s;
            for (; i + 8 <= e; i += 8) {
                int c0 = clist[i], c1 = clist[i + 1], c2 = clist[i + 2], c3 = clist[i + 3];
                int c4 = clist[i + 4], c5 = clist[i + 5], c6 = clist[i + 6], c7 = clist[i + 7];
                float2 v0 = ((const float2*)(x + (size_t)c0 * F))[lane];
                float2 v1 = ((const float2*)(x + (size_t)c1 * F))[lane];
                float2 v2 = ((const float2*)(x + (size_t)c2 * F))[lane];
                float2 v3 = ((const float2*)(x + (size_t)c3 * F))[lane];
                float2 v4 = ((const float2*)(x + (size_t)c4 * F))[lane];
                float2 v5 = ((const float2*)(x + (size_t)c5 * F))[lane];
                float2 v6 = ((const float2*)(x + (size_t)c6 * F))[lane];
                float2 v7 = ((const float2*)(x + (size_t)c7 * F))[lane];
                acc[j].x += ((v0.x + v1.x) + (v2.x + v3.x)) + ((v4.x + v5.x) + (v6.x + v7.x));
                acc[j].y += ((v0.y + v1.y) + (v2.y + v3.y)) + ((v4.y + v5.y) + (v6.y + v7.y));
            }
            for (; i < e; ++i) {
                int c = clist[i];
                float2 v = ((const float2*)(x + (size_t)c * F))[lane];
                acc[j].x += v.x; acc[j].y += v.y;
            }
        }
        __syncthreads();
    }
#pragma unroll
    for (int j = 0; j < 16; j++) {
        int g = nb0 + wave * 16 + j;
        if (g < n) ((float2*)(h0 + (size_t)g * F))[lane] = acc[j];
    }
}

// ---------- K5: GEMM1 (h0 @ W1^T + b1) + BN partial stats ----------
__global__ __launch_bounds__(256, 4) void gemm1_stats_kernel(const float* __restrict__ h0,
                                                             const float* __restrict__ wt,
                                                             const float* __restrict__ b1,
                                                             float* __restrict__ h1,
                                                             float* __restrict__ stats, int n) {
    __shared__ float xs[64 * F];   // 32KB x-tile
    int tid = threadIdx.x;
    int tb = blockIdx.x * 64;
    float4* xs4 = (float4*)xs;
#pragma unroll
    for (int j = 0; j < 8; j++) {
        int idx = tid + 256 * j;
        int row = idx >> 5;
        int g = tb + row; if (g >= n) g = n - 1;
        xs4[idx] = ((const float4*)(h0 + (size_t)g * F))[idx & 31];
    }
    __syncthreads();

    int wave = tid >> 6, lane = tid & 63;
    int rb = wave * 16;
    int c0 = lane * 2;
    float2 bb = *(const float2*)(b1 + c0);
    float acc[16][2];
#pragma unroll
    for (int j = 0; j < 16; j++) { acc[j][0] = bb.x; acc[j][1] = bb.y; }

    for (int k4 = 0; k4 < F; k4 += 4) {
        float2 wv[4];
#pragma unroll
        for (int kk = 0; kk < 4; kk++)
            wv[kk] = *(const float2*)(wt + (size_t)(k4 + kk) * F + c0);
#pragma unroll
        for (int half = 0; half < 2; half++) {
            float4 xv[8];
#pragma unroll
            for (int j = 0; j < 8; j++)
                xv[j] = *(const float4*)(xs + (rb + half * 8 + j) * F + k4);
#pragma unroll
            for (int kk = 0; kk < 4; kk++) {
#pragma unroll
                for (int j = 0; j < 8; j++) {
                    float xk = ((const float*)&xv[j])[kk];
                    int r = half * 8 + j;
                    acc[r][0] = fmaf(xk, wv[kk].x, acc[r][0]);
                    acc[r][1] = fmaf(xk, wv[kk].y, acc[r][1]);
                }
            }
        }
    }

    float sum0 = 0, sum1 = 0, sq0 = 0, sq1 = 0;
#pragma unroll
    for (int j = 0; j < 16; j++) {
        int r = tb + rb + j;
        if (r < n) {
            float a0 = acc[j][0], a1 = acc[j][1];
            ((float2*)(h1 + (size_t)r * F))[lane] = make_float2(a0, a1);
            sum0 += a0; sum1 += a1; sq0 += a0 * a0; sq1 += a1 * a1;
        }
    }
    __syncthreads();
    xs[wave * F + c0] = sum0; xs[wave * F + c0 + 1] = sum1;
    xs[512 + wave * F + c0] = sq0; xs[512 + wave * F + c0 + 1] = sq1;
    __syncthreads();
    if (wave == 0) {
        float S0 = 0, S1 = 0, Q0 = 0, Q1 = 0;
#pragma unroll
        for (int w = 0; w < 4; w++) {
            S0 += xs[w * F + c0]; S1 += xs[w * F + c0 + 1];
            Q0 += xs[512 + w * F + c0]; Q1 += xs[512 + w * F + c0 + 1];
        }
        atomicAdd(&stats[c0], S0); atomicAdd(&stats[c0 + 1], S1);
        atomicAdd(&stats[F + c0], Q0); atomicAdd(&stats[F + c0 + 1], Q1);
    }
}

// ---------- K6: finalize BN -> scale/shift ----------
__global__ void bn_finalize_kernel(const float* __restrict__ stats, const float* __restrict__ gamma,
                                   const float* __restrict__ beta, float* __restrict__ ss, int n) {
    int c = threadIdx.x;
    float inv_n = 1.0f / (float)n;
    float mu = stats[c] * inv_n;
    float var = stats[F + c] * inv_n - mu * mu;
    var = fmaxf(var, 0.0f);
    float rs = rsqrtf(var + 1e-5f);
    float s = gamma[c] * rs;
    ss[c] = s;
    ss[F + c] = beta[c] - mu * s;
}

// ---------- K7: GEMM2, BN+ReLU fused into the LDS staging ----------
__global__ __launch_bounds__(256, 4) void gemm2_kernel(const float* __restrict__ wt,
                                                       const float* __restrict__ b2,
                                                       const float* __restrict__ ss,
                                                       float* hbuf, int n) {
    __shared__ float xs[64 * F];
    int tid = threadIdx.x;
    int tb = blockIdx.x * 64;
    int kg = tid & 31;
    float4 sv = *(const float4*)(ss + kg * 4);
    float4 tv = *(const float4*)(ss + F + kg * 4);
    float4* xs4 = (float4*)xs;
#pragma unroll
    for (int j = 0; j < 8; j++) {
        int idx = tid + 256 * j;
        int row = idx >> 5;
        int g = tb + row; if (g >= n) g = n - 1;
        float4 v = ((const float4*)(hbuf + (size_t)g * F))[idx & 31];
        v.x = fmaxf(fmaf(v.x, sv.x, tv.x), 0.0f);
        v.y = fmaxf(fmaf(v.y, sv.y, tv.y), 0.0f);
        v.z = fmaxf(fmaf(v.z, sv.z, tv.z), 0.0f);
        v.w = fmaxf(fmaf(v.w, sv.w, tv.w), 0.0f);
        xs4[idx] = v;
    }
    __syncthreads();

    int wave = tid >> 6, lane = tid & 63;
    int rb = wave * 16;
    int c0 = lane * 2;
    float2 bb = *(const float2*)(b2 + c0);
    float acc[16][2];
#pragma unroll
    for (int j = 0; j < 16; j++) { acc[j][0] = bb.x; acc[j][1] = bb.y; }

    for (int k4 = 0; k4 < F; k4 += 4) {
        float2 wv[4];
#pragma unroll
        for (int kk = 0; kk < 4; kk++)
            wv[kk] = *(const float2*)(wt + (size_t)(k4 + kk) * F + c0);
#pragma unroll
        for (int half = 0; half < 2; half++) {
            float4 xv[8];
#pragma unroll
            for (int j = 0; j < 8; j++)
                xv[j] = *(const float4*)(xs + (rb + half * 8 + j) * F + k4);
#pragma unroll
            for (int kk = 0; kk < 4; kk++) {
#pragma unroll
                for (int j = 0; j < 8; j++) {
                    float xk = ((const float*)&xv[j])[kk];
                    int r = half * 8 + j;
                    acc[r][0] = fmaf(xk, wv[kk].x, acc[r][0]);
                    acc[r][1] = fmaf(xk, wv[kk].y, acc[r][1]);
                }
            }
        }
    }
#pragma unroll
    for (int j = 0; j < 16; j++) {
        int r = tb + rb + j;
        if (r < n)
            ((float2*)(hbuf + (size_t)r * F))[lane] = make_float2(acc[j][0], acc[j][1]);
    }
}

extern "C" void kernel_launch(void* const* d_in, const int* in_sizes, int n_in,
                              void* d_out, int out_size, void* d_ws, size_t ws_size,
                              hipStream_t stream) {
    const float* x     = (const float*)d_in[0];
    const int*   ei    = (const int*)d_in[1];
    const float* eps   = (const float*)d_in[2];
    const float* W1    = (const float*)d_in[3];
    const float* b1    = (const float*)d_in[4];
    const float* gamma = (const float*)d_in[5];
    const float* beta  = (const float*)d_in[6];
    const float* W2    = (const float*)d_in[7];
    const float* b2    = (const float*)d_in[8];
    float* out = (float*)d_out;

    const int E = in_sizes[1] / 2;
    const int n = in_sizes[0] / F;
    const int nbuk = (n + NPB - 1) / NPB;   // 1563

    char* w = (char*)d_ws;
    auto alloc = [&](size_t bytes) -> void* {
        void* p = (void*)w;
        w += (bytes + 255) & ~(size_t)255;
        return p;
    };
    int*   bucketCnt = (int*)alloc((size_t)nbuk * 4);
    int*   bOffs     = (int*)alloc((size_t)(nbuk + 1) * 4);
    int*   gcursor   = (int*)alloc((size_t)nbuk * 4);
    float* stats     = (float*)alloc(256 * 4);
    float* ss        = (float*)alloc(256 * 4);
    float* w1t       = (float*)alloc(F * F * 4);
    float* w2t       = (float*)alloc(F * F * 4);
    int*   recbuf    = (int*)alloc((size_t)E * 4);
    float* h0        = (float*)alloc((size_t)n * F * 4);

    const int* rows = ei;
    const int* cols = ei + E;

    hipMemsetAsync(bucketCnt, 0, (size_t)nbuk * 4, stream);
    hipMemsetAsync(stats, 0, 256 * 4, stream);

    transpose_w_kernel<<<64, 256, 0, stream>>>(W1, W2, w1t, w2t);
    bucket_hist_kernel<<<256, 256, nbuk * 4, stream>>>(rows, bucketCnt, E, nbuk);
    scan_buckets_kernel<<<1, 256, 0, stream>>>(bucketCnt, bOffs, gcursor, nbuk);
    binned_scatter_kernel<<<128, 1024, nbuk * 8, stream>>>(rows, cols, gcursor, recbuf, E, nbuk);
    agg_fused_kernel<<<nbuk, 256, 0, stream>>>(x, bOffs, recbuf, eps, h0, n);

    int ntiles = (n + 63) / 64;
    gemm1_stats_kernel<<<ntiles, 256, 0, stream>>>(h0, w1t, b1, out, stats, n);
    bn_finalize_kernel<<<1, 128, 0, stream>>>(stats, gamma, beta, ss, n);
    gemm2_kernel<<<ntiles, 256, 0, stream>>>(w2t, b2, ss, out, n);
}

// Round 4
// 433.672 us; speedup vs baseline: 1.5566x; 1.0398x over previous
//
#include <hip/hip_runtime.h>

// GIN layer: agg = segment_sum(x[col], row); h = (1+eps)*x + agg;
// h = h@W1.T + b1; BN(train) ; ReLU ; out = h@W2.T + b2
// N=100000, E=1600000, F=128. All fp32.

#define F 128
#define NPB 64          // nodes per bucket

// ---------- K0: transpose W1,W2 into ws ----------
__global__ void transpose_w_kernel(const float* __restrict__ W1, const float* __restrict__ W2,
                                   float* __restrict__ w1t, float* __restrict__ w2t) {
    int idx = blockIdx.x * 256 + threadIdx.x;   // 16384 threads
    int k = idx >> 7, c = idx & 127;
    w1t[idx] = W1[c * F + k];
    w2t[idx] = W2[c * F + k];
}

// ---------- K1: bucket histogram (LDS-aggregated) ----------
__global__ __launch_bounds__(256) void bucket_hist_kernel(const int* __restrict__ rows,
                                                          int* __restrict__ bucketCnt,
                                                          int E, int nbuk) {
    extern __shared__ int bh[];     // nbuk ints
    int tid = threadIdx.x;
    for (int i = tid; i < nbuk; i += 256) bh[i] = 0;
    __syncthreads();
    int stride = gridDim.x * 256;
    for (int i = blockIdx.x * 256 + tid; i < E; i += stride)
        atomicAdd(&bh[rows[i] >> 6], 1);
    __syncthreads();
    for (int b = tid; b < nbuk; b += 256) {
        int c = bh[b];
        if (c) atomicAdd(&bucketCnt[b], c);
    }
}

// ---------- K2: exclusive scan of bucket counts -> offsets + cursor ----------
__global__ void scan_buckets_kernel(const int* __restrict__ bucketCnt, int* __restrict__ bOffs,
                                    int* __restrict__ gcursor, int nbuk) {
    const int SEG = 7;   // 256*7 = 1792 >= 1563
    __shared__ int tmp[256];
    int t = threadIdx.x;
    int base = t * SEG;
    int v[SEG], s = 0;
#pragma unroll
    for (int j = 0; j < SEG; j++) {
        int idx = base + j;
        v[j] = (idx < nbuk) ? bucketCnt[idx] : 0;
        s += v[j];
    }
    tmp[t] = s;
    __syncthreads();
    for (int off = 1; off < 256; off <<= 1) {
        int u = (t >= off) ? tmp[t - off] : 0;
        __syncthreads();
        tmp[t] += u;
        __syncthreads();
    }
    int run = tmp[t] - s;
#pragma unroll
    for (int j = 0; j < SEG; j++) {
        int idx = base + j;
        if (idx < nbuk) { bOffs[idx] = run; gcursor[idx] = run; }
        run += v[j];
    }
    if (t == 255) bOffs[nbuk] = tmp[255];
}

// ---------- K3: binned scatter: records (col<<6 | row&63) grouped by bucket ----------
__global__ __launch_bounds__(1024) void binned_scatter_kernel(const int* __restrict__ rows,
                                                              const int* __restrict__ cols,
                                                              int* __restrict__ gcursor,
                                                              int* __restrict__ recbuf,
                                                              int E, int nbuk) {
    extern __shared__ int sm[];     // bh[nbuk], gb[nbuk]
    int* bh = sm;
    int* gb = sm + nbuk;
    int tid = threadIdx.x;
    int chunk = (E + gridDim.x - 1) / gridDim.x;
    int e0 = blockIdx.x * chunk;
    int e1 = min(E, e0 + chunk);
    for (int i = tid; i < nbuk; i += 1024) bh[i] = 0;
    __syncthreads();
    for (int i = e0 + tid; i < e1; i += 1024)
        atomicAdd(&bh[rows[i] >> 6], 1);
    __syncthreads();
    for (int b = tid; b < nbuk; b += 1024) {
        int c = bh[b];
        gb[b] = c ? atomicAdd(&gcursor[b], c) : 0;
        bh[b] = 0;
    }
    __syncthreads();
    for (int i = e0 + tid; i < e1; i += 1024) {
        int r = rows[i], c = cols[i];
        int k = r >> 6;
        int rk = atomicAdd(&bh[k], 1);
        recbuf[gb[k] + rk] = (c << 6) | (r & 63);
    }
}

// ---------- K3b: per-bucket counting sort -> node-sorted clist + per-node offs ----------
// One block per bucket. Two global passes over the bucket's records (L2-hot).
__global__ __launch_bounds__(256) void bucket_sort_kernel(const int* __restrict__ recbuf,
                                                          const int* __restrict__ bOffs,
                                                          int* __restrict__ clist,
                                                          int* __restrict__ offs,
                                                          int n, int nbuk) {
    __shared__ int hist[NPB];
    __shared__ int cur[NPB];
    int b = blockIdx.x, tid = threadIdx.x;
    int base = bOffs[b];
    int cnt = bOffs[b + 1] - base;
    if (tid < NPB) hist[tid] = 0;
    __syncthreads();
    for (int i = tid; i < cnt; i += 256) atomicAdd(&hist[recbuf[base + i] & 63], 1);
    __syncthreads();
    if (tid < 64) {
        int h = hist[tid], v = h;
#pragma unroll
        for (int off = 1; off < 64; off <<= 1) {
            int u = __shfl_up(v, off, 64);
            if (tid >= off) v += u;
        }
        cur[tid] = v - h;                       // exclusive prefix
        int g = b * NPB + tid;
        if (g < n) offs[g] = base + v - h;
    }
    if (b == 0 && tid == 0) offs[n] = bOffs[nbuk];
    __syncthreads();
    for (int i = tid; i < cnt; i += 256) {
        int r = recbuf[base + i];
        int p = atomicAdd(&cur[r & 63], 1);
        clist[base + p] = r >> 6;
    }
}

// ---------- K4: gather-aggregate: h0 = (1+eps)*x + sum_neighbors x ----------
// One wave per node. float4/lane; lower half handles even-index neighbors,
// upper half odd-index; 8 KB in flight per wave; cross-half shfl reduce.
__global__ __launch_bounds__(256) void agg_kernel(const float* __restrict__ x,
                                                  const int* __restrict__ offs,
                                                  const int* __restrict__ clist,
                                                  const float* __restrict__ epsPtr,
                                                  float* __restrict__ h0, int n) {
    int wave = threadIdx.x >> 6, lane = threadIdx.x & 63;
    int node = blockIdx.x * 4 + wave;
    if (node >= n) return;
    int half = lane >> 5, q = lane & 31;
    float4 acc = make_float4(0.f, 0.f, 0.f, 0.f);
    int s = offs[node], e = offs[node + 1];
    int i = s;
    for (; i + 16 <= e; i += 16) {
        int c[8];
#pragma unroll
        for (int u = 0; u < 8; u++) c[u] = clist[i + 2 * u + half];
        float4 v[8];
#pragma unroll
        for (int u = 0; u < 8; u++) v[u] = *(const float4*)(x + (size_t)c[u] * F + q * 4);
        float4 s01, s23, s45, s67, sA, sB;
        s01.x = v[0].x + v[1].x; s01.y = v[0].y + v[1].y; s01.z = v[0].z + v[1].z; s01.w = v[0].w + v[1].w;
        s23.x = v[2].x + v[3].x; s23.y = v[2].y + v[3].y; s23.z = v[2].z + v[3].z; s23.w = v[2].w + v[3].w;
        s45.x = v[4].x + v[5].x; s45.y = v[4].y + v[5].y; s45.z = v[4].z + v[5].z; s45.w = v[4].w + v[5].w;
        s67.x = v[6].x + v[7].x; s67.y = v[6].y + v[7].y; s67.z = v[6].z + v[7].z; s67.w = v[6].w + v[7].w;
        sA.x = s01.x + s23.x; sA.y = s01.y + s23.y; sA.z = s01.z + s23.z; sA.w = s01.w + s23.w;
        sB.x = s45.x + s67.x; sB.y = s45.y + s67.y; sB.z = s45.z + s67.z; sB.w = s45.w + s67.w;
        acc.x += sA.x + sB.x; acc.y += sA.y + sB.y; acc.z += sA.z + sB.z; acc.w += sA.w + sB.w;
    }
    for (; i + 2 <= e; i += 2) {
        int c = clist[i + half];
        float4 v = *(const float4*)(x + (size_t)c * F + q * 4);
        acc.x += v.x; acc.y += v.y; acc.z += v.z; acc.w += v.w;
    }
    if (i < e && half == 0) {
        int c = clist[i];
        float4 v = *(const float4*)(x + (size_t)c * F + q * 4);
        acc.x += v.x; acc.y += v.y; acc.z += v.z; acc.w += v.w;
    }
    // cross-half reduce (lanes 0-31 get the total)
    acc.x += __shfl_down(acc.x, 32, 64);
    acc.y += __shfl_down(acc.y, 32, 64);
    acc.z += __shfl_down(acc.z, 32, 64);
    acc.w += __shfl_down(acc.w, 32, 64);
    if (half == 0) {
        float sc = 1.0f + epsPtr[0];
        float4 xv = *(const float4*)(x + (size_t)node * F + q * 4);
        acc.x = fmaf(sc, xv.x, acc.x);
        acc.y = fmaf(sc, xv.y, acc.y);
        acc.z = fmaf(sc, xv.z, acc.z);
        acc.w = fmaf(sc, xv.w, acc.w);
        *(float4*)(h0 + (size_t)node * F + q * 4) = acc;
    }
}

// ---------- K5: GEMM1 (h0 @ W1^T + b1) + BN partial stats ----------
__global__ __launch_bounds__(256, 4) void gemm1_stats_kernel(const float* __restrict__ h0,
                                                             const float* __restrict__ wt,
                                                             const float* __restrict__ b1,
                                                             float* __restrict__ h1,
                                                             float* __restrict__ stats, int n) {
    __shared__ float xs[64 * F];   // 32KB x-tile
    int tid = threadIdx.x;
    int tb = blockIdx.x * 64;
    float4* xs4 = (float4*)xs;
#pragma unroll
    for (int j = 0; j < 8; j++) {
        int idx = tid + 256 * j;
        int row = idx >> 5;
        int g = tb + row; if (g >= n) g = n - 1;
        xs4[idx] = ((const float4*)(h0 + (size_t)g * F))[idx & 31];
    }
    __syncthreads();

    int wave = tid >> 6, lane = tid & 63;
    int rb = wave * 16;
    int c0 = lane * 2;
    float2 bb = *(const float2*)(b1 + c0);
    float acc[16][2];
#pragma unroll
    for (int j = 0; j < 16; j++) { acc[j][0] = bb.x; acc[j][1] = bb.y; }

    for (int k4 = 0; k4 < F; k4 += 4) {
        float2 wv[4];
#pragma unroll
        for (int kk = 0; kk < 4; kk++)
            wv[kk] = *(const float2*)(wt + (size_t)(k4 + kk) * F + c0);
#pragma unroll
        for (int half = 0; half < 2; half++) {
            float4 xv[8];
#pragma unroll
            for (int j = 0; j < 8; j++)
                xv[j] = *(const float4*)(xs + (rb + half * 8 + j) * F + k4);
#pragma unroll
            for (int kk = 0; kk < 4; kk++) {
#pragma unroll
                for (int j = 0; j < 8; j++) {
                    float xk = ((const float*)&xv[j])[kk];
                    int r = half * 8 + j;
                    acc[r][0] = fmaf(xk, wv[kk].x, acc[r][0]);
                    acc[r][1] = fmaf(xk, wv[kk].y, acc[r][1]);
                }
            }
        }
    }

    float sum0 = 0, sum1 = 0, sq0 = 0, sq1 = 0;
#pragma unroll
    for (int j = 0; j < 16; j++) {
        int r = tb + rb + j;
        if (r < n) {
            float a0 = acc[j][0], a1 = acc[j][1];
            ((float2*)(h1 + (size_t)r * F))[lane] = make_float2(a0, a1);
            sum0 += a0; sum1 += a1; sq0 += a0 * a0; sq1 += a1 * a1;
        }
    }
    __syncthreads();
    xs[wave * F + c0] = sum0; xs[wave * F + c0 + 1] = sum1;
    xs[512 + wave * F + c0] = sq0; xs[512 + wave * F + c0 + 1] = sq1;
    __syncthreads();
    if (wave == 0) {
        float S0 = 0, S1 = 0, Q0 = 0, Q1 = 0;
#pragma unroll
        for (int w = 0; w < 4; w++) {
            S0 += xs[w * F + c0]; S1 += xs[w * F + c0 + 1];
            Q0 += xs[512 + w * F + c0]; Q1 += xs[512 + w * F + c0 + 1];
        }
        atomicAdd(&stats[c0], S0); atomicAdd(&stats[c0 + 1], S1);
        atomicAdd(&stats[F + c0], Q0); atomicAdd(&stats[F + c0 + 1], Q1);
    }
}

// ---------- K6: finalize BN -> scale/shift ----------
__global__ void bn_finalize_kernel(const float* __restrict__ stats, const float* __restrict__ gamma,
                                   const float* __restrict__ beta, float* __restrict__ ss, int n) {
    int c = threadIdx.x;
    float inv_n = 1.0f / (float)n;
    float mu = stats[c] * inv_n;
    float var = stats[F + c] * inv_n - mu * mu;
    var = fmaxf(var, 0.0f);
    float rs = rsqrtf(var + 1e-5f);
    float s = gamma[c] * rs;
    ss[c] = s;
    ss[F + c] = beta[c] - mu * s;
}

// ---------- K7: GEMM2, BN+ReLU fused into the LDS staging ----------
__global__ __launch_bounds__(256, 4) void gemm2_kernel(const float* __restrict__ wt,
                                                       const float* __restrict__ b2,
                                                       const float* __restrict__ ss,
                                                       float* hbuf, int n) {
    __shared__ float xs[64 * F];
    int tid = threadIdx.x;
    int tb = blockIdx.x * 64;
    int kg = tid & 31;
    float4 sv = *(const float4*)(ss + kg * 4);
    float4 tv = *(const float4*)(ss + F + kg * 4);
    float4* xs4 = (float4*)xs;
#pragma unroll
    for (int j = 0; j < 8; j++) {
        int idx = tid + 256 * j;
        int row = idx >> 5;
        int g = tb + row; if (g >= n) g = n - 1;
        float4 v = ((const float4*)(hbuf + (size_t)g * F))[idx & 31];
        v.x = fmaxf(fmaf(v.x, sv.x, tv.x), 0.0f);
        v.y = fmaxf(fmaf(v.y, sv.y, tv.y), 0.0f);
        v.z = fmaxf(fmaf(v.z, sv.z, tv.z), 0.0f);
        v.w = fmaxf(fmaf(v.w, sv.w, tv.w), 0.0f);
        xs4[idx] = v;
    }
    __syncthreads();

    int wave = tid >> 6, lane = tid & 63;
    int rb = wave * 16;
    int c0 = lane * 2;
    float2 bb = *(const float2*)(b2 + c0);
    float acc[16][2];
#pragma unroll
    for (int j = 0; j < 16; j++) { acc[j][0] = bb.x; acc[j][1] = bb.y; }

    for (int k4 = 0; k4 < F; k4 += 4) {
        float2 wv[4];
#pragma unroll
        for (int kk = 0; kk < 4; kk++)
            wv[kk] = *(const float2*)(wt + (size_t)(k4 + kk) * F + c0);
#pragma unroll
        for (int half = 0; half < 2; half++) {
            float4 xv[8];
#pragma unroll
            for (int j = 0; j < 8; j++)
                xv[j] = *(const float4*)(xs + (rb + half * 8 + j) * F + k4);
#pragma unroll
            for (int kk = 0; kk < 4; kk++) {
#pragma unroll
                for (int j = 0; j < 8; j++) {
                    float xk = ((const float*)&xv[j])[kk];
                    int r = half * 8 + j;
                    acc[r][0] = fmaf(xk, wv[kk].x, acc[r][0]);
                    acc[r][1] = fmaf(xk, wv[kk].y, acc[r][1]);
                }
            }
        }
    }
#pragma unroll
    for (int j = 0; j < 16; j++) {
        int r = tb + rb + j;
        if (r < n)
            ((float2*)(hbuf + (size_t)r * F))[lane] = make_float2(acc[j][0], acc[j][1]);
    }
}

extern "C" void kernel_launch(void* const* d_in, const int* in_sizes, int n_in,
                              void* d_out, int out_size, void* d_ws, size_t ws_size,
                              hipStream_t stream) {
    const float* x     = (const float*)d_in[0];
    const int*   ei    = (const int*)d_in[1];
    const float* eps   = (const float*)d_in[2];
    const float* W1    = (const float*)d_in[3];
    const float* b1    = (const float*)d_in[4];
    const float* gamma = (const float*)d_in[5];
    const float* beta  = (const float*)d_in[6];
    const float* W2    = (const float*)d_in[7];
    const float* b2    = (const float*)d_in[8];
    float* out = (float*)d_out;

    const int E = in_sizes[1] / 2;
    const int n = in_sizes[0] / F;
    const int nbuk = (n + NPB - 1) / NPB;   // 1563

    char* w = (char*)d_ws;
    auto alloc = [&](size_t bytes) -> void* {
        void* p = (void*)w;
        w += (bytes + 255) & ~(size_t)255;
        return p;
    };
    int*   bucketCnt = (int*)alloc((size_t)nbuk * 4);
    int*   bOffs     = (int*)alloc((size_t)(nbuk + 1) * 4);
    int*   gcursor   = (int*)alloc((size_t)nbuk * 4);
    int*   offs      = (int*)alloc((size_t)(n + 1) * 4);
    float* stats     = (float*)alloc(256 * 4);
    float* ss        = (float*)alloc(256 * 4);
    float* w1t       = (float*)alloc(F * F * 4);
    float* w2t       = (float*)alloc(F * F * 4);
    int*   recbuf    = (int*)alloc((size_t)E * 4);
    int*   clist     = (int*)alloc((size_t)E * 4);
    float* h0        = (float*)alloc((size_t)n * F * 4);

    const int* rows = ei;
    const int* cols = ei + E;

    hipMemsetAsync(bucketCnt, 0, (size_t)nbuk * 4, stream);
    hipMemsetAsync(stats, 0, 256 * 4, stream);

    transpose_w_kernel<<<64, 256, 0, stream>>>(W1, W2, w1t, w2t);
    bucket_hist_kernel<<<256, 256, nbuk * 4, stream>>>(rows, bucketCnt, E, nbuk);
    scan_buckets_kernel<<<1, 256, 0, stream>>>(bucketCnt, bOffs, gcursor, nbuk);
    binned_scatter_kernel<<<128, 1024, nbuk * 8, stream>>>(rows, cols, gcursor, recbuf, E, nbuk);
    bucket_sort_kernel<<<nbuk, 256, 0, stream>>>(recbuf, bOffs, clist, offs, n, nbuk);
    agg_kernel<<<(n + 3) / 4, 256, 0, stream>>>(x, offs, clist, eps, h0, n);

    int ntiles = (n + 63) / 64;
    gemm1_stats_kernel<<<ntiles, 256, 0, stream>>>(h0, w1t, b1, out, stats, n);
    bn_finalize_kernel<<<1, 128, 0, stream>>>(stats, gamma, beta, ss, n);
    gemm2_kernel<<<ntiles, 256, 0, stream>>>(w2t, b2, ss, out, n);
}

// Round 5
// 326.502 us; speedup vs baseline: 2.0675x; 1.3282x over previous
//
#include <hip/hip_runtime.h>

// GIN layer: agg = segment_sum(x[col], row); h = (1+eps)*x + agg;
// h = h@W1.T + b1; BN(train); ReLU; out = h@W2.T + b2
// N=100000, E=1600000, F=128. Inputs fp32; internal bf16 + MFMA.

#define F 128
#define NPB 64          // nodes per bucket

typedef __attribute__((ext_vector_type(8))) short short8;
typedef __attribute__((ext_vector_type(4))) float float4v;

__device__ inline float b2f(unsigned short u) {
    union { unsigned int i; float f; } v; v.i = ((unsigned int)u) << 16; return v.f;
}
__device__ inline unsigned short f2b(float f) {
    union { float f; unsigned int i; } v; v.f = f;
    unsigned int r = v.i + 0x7FFFu + ((v.i >> 16) & 1u);
    return (unsigned short)(r >> 16);
}

// ---------- K0a: convert x -> bf16 ----------
__global__ __launch_bounds__(256) void conv_x_kernel(const float* __restrict__ x,
                                                     unsigned short* __restrict__ xh, int total) {
    int i = (blockIdx.x * 256 + threadIdx.x) * 8;
    if (i >= total) return;
    float4 v0 = *(const float4*)(x + i);
    float4 v1 = *(const float4*)(x + i + 4);
    short8 o;
    o[0] = (short)f2b(v0.x); o[1] = (short)f2b(v0.y); o[2] = (short)f2b(v0.z); o[3] = (short)f2b(v0.w);
    o[4] = (short)f2b(v1.x); o[5] = (short)f2b(v1.y); o[6] = (short)f2b(v1.z); o[7] = (short)f2b(v1.w);
    *(short8*)(xh + i) = o;
}

// ---------- K0b: convert W1,W2 -> bf16 (keep row-major [c][k]) ----------
__global__ void conv_w_kernel(const float* __restrict__ W1, const float* __restrict__ W2,
                              unsigned short* __restrict__ w1h, unsigned short* __restrict__ w2h) {
    int idx = blockIdx.x * 256 + threadIdx.x;   // 16384 threads
    w1h[idx] = f2b(W1[idx]);
    w2h[idx] = f2b(W2[idx]);
}

// ---------- K1: bucket histogram (LDS-aggregated) ----------
__global__ __launch_bounds__(256) void bucket_hist_kernel(const int* __restrict__ rows,
                                                          int* __restrict__ bucketCnt,
                                                          int E, int nbuk) {
    extern __shared__ int bh[];
    int tid = threadIdx.x;
    for (int i = tid; i < nbuk; i += 256) bh[i] = 0;
    __syncthreads();
    int stride = gridDim.x * 256;
    for (int i = blockIdx.x * 256 + tid; i < E; i += stride)
        atomicAdd(&bh[rows[i] >> 6], 1);
    __syncthreads();
    for (int b = tid; b < nbuk; b += 256) {
        int c = bh[b];
        if (c) atomicAdd(&bucketCnt[b], c);
    }
}

// ---------- K2: exclusive scan of bucket counts ----------
__global__ void scan_buckets_kernel(const int* __restrict__ bucketCnt, int* __restrict__ bOffs,
                                    int* __restrict__ gcursor, int nbuk) {
    const int SEG = 7;
    __shared__ int tmp[256];
    int t = threadIdx.x;
    int base = t * SEG;
    int v[SEG], s = 0;
#pragma unroll
    for (int j = 0; j < SEG; j++) {
        int idx = base + j;
        v[j] = (idx < nbuk) ? bucketCnt[idx] : 0;
        s += v[j];
    }
    tmp[t] = s;
    __syncthreads();
    for (int off = 1; off < 256; off <<= 1) {
        int u = (t >= off) ? tmp[t - off] : 0;
        __syncthreads();
        tmp[t] += u;
        __syncthreads();
    }
    int run = tmp[t] - s;
#pragma unroll
    for (int j = 0; j < SEG; j++) {
        int idx = base + j;
        if (idx < nbuk) { bOffs[idx] = run; gcursor[idx] = run; }
        run += v[j];
    }
    if (t == 255) bOffs[nbuk] = tmp[255];
}

// ---------- K3: binned scatter ----------
__global__ __launch_bounds__(1024) void binned_scatter_kernel(const int* __restrict__ rows,
                                                              const int* __restrict__ cols,
                                                              int* __restrict__ gcursor,
                                                              int* __restrict__ recbuf,
                                                              int E, int nbuk) {
    extern __shared__ int sm[];
    int* bh = sm;
    int* gb = sm + nbuk;
    int tid = threadIdx.x;
    int chunk = (E + gridDim.x - 1) / gridDim.x;
    int e0 = blockIdx.x * chunk;
    int e1 = min(E, e0 + chunk);
    for (int i = tid; i < nbuk; i += 1024) bh[i] = 0;
    __syncthreads();
    for (int i = e0 + tid; i < e1; i += 1024)
        atomicAdd(&bh[rows[i] >> 6], 1);
    __syncthreads();
    for (int b = tid; b < nbuk; b += 1024) {
        int c = bh[b];
        gb[b] = c ? atomicAdd(&gcursor[b], c) : 0;
        bh[b] = 0;
    }
    __syncthreads();
    for (int i = e0 + tid; i < e1; i += 1024) {
        int r = rows[i], c = cols[i];
        int k = r >> 6;
        int rk = atomicAdd(&bh[k], 1);
        recbuf[gb[k] + rk] = (c << 6) | (r & 63);
    }
}

// ---------- K3b: per-bucket counting sort ----------
__global__ __launch_bounds__(256) void bucket_sort_kernel(const int* __restrict__ recbuf,
                                                          const int* __restrict__ bOffs,
                                                          int* __restrict__ clist,
                                                          int* __restrict__ offs,
                                                          int n, int nbuk) {
    __shared__ int hist[NPB];
    __shared__ int cur[NPB];
    int b = blockIdx.x, tid = threadIdx.x;
    int base = bOffs[b];
    int cnt = bOffs[b + 1] - base;
    if (tid < NPB) hist[tid] = 0;
    __syncthreads();
    for (int i = tid; i < cnt; i += 256) atomicAdd(&hist[recbuf[base + i] & 63], 1);
    __syncthreads();
    if (tid < 64) {
        int h = hist[tid], v = h;
#pragma unroll
        for (int off = 1; off < 64; off <<= 1) {
            int u = __shfl_up(v, off, 64);
            if (tid >= off) v += u;
        }
        cur[tid] = v - h;
        int g = b * NPB + tid;
        if (g < n) offs[g] = base + v - h;
    }
    if (b == 0 && tid == 0) offs[n] = bOffs[nbuk];
    __syncthreads();
    for (int i = tid; i < cnt; i += 256) {
        int r = recbuf[base + i];
        int p = atomicAdd(&cur[r & 63], 1);
        clist[base + p] = r >> 6;
    }
}

// ---------- K4: gather-aggregate in bf16: h0h = bf16((1+eps)*x + sum_nb x) ----------
// One wave per node; halves split even/odd neighbors; ushort4 (4ch)/lane per row.
__global__ __launch_bounds__(256) void agg_kernel(const unsigned short* __restrict__ xh,
                                                  const int* __restrict__ offs,
                                                  const int* __restrict__ clist,
                                                  const float* __restrict__ epsPtr,
                                                  unsigned short* __restrict__ h0h, int n) {
    int wave = threadIdx.x >> 6, lane = threadIdx.x & 63;
    int node = blockIdx.x * 4 + wave;
    if (node >= n) return;
    int half = lane >> 5, q = lane & 31;
    const ushort4* xh4 = (const ushort4*)xh;
    float4 acc = make_float4(0.f, 0.f, 0.f, 0.f);
    int s = offs[node], e = offs[node + 1];
    int i = s;
    for (; i + 16 <= e; i += 16) {
        int c[8];
#pragma unroll
        for (int u = 0; u < 8; u++) c[u] = clist[i + 2 * u + half];
        ushort4 v[8];
#pragma unroll
        for (int u = 0; u < 8; u++) v[u] = xh4[(size_t)c[u] * 32 + q];
#pragma unroll
        for (int u = 0; u < 8; u++) {
            acc.x += b2f(v[u].x); acc.y += b2f(v[u].y);
            acc.z += b2f(v[u].z); acc.w += b2f(v[u].w);
        }
    }
    for (; i + 2 <= e; i += 2) {
        int c = clist[i + half];
        ushort4 v = xh4[(size_t)c * 32 + q];
        acc.x += b2f(v.x); acc.y += b2f(v.y); acc.z += b2f(v.z); acc.w += b2f(v.w);
    }
    if (i < e && half == 0) {
        int c = clist[i];
        ushort4 v = xh4[(size_t)c * 32 + q];
        acc.x += b2f(v.x); acc.y += b2f(v.y); acc.z += b2f(v.z); acc.w += b2f(v.w);
    }
    acc.x += __shfl_down(acc.x, 32, 64);
    acc.y += __shfl_down(acc.y, 32, 64);
    acc.z += __shfl_down(acc.z, 32, 64);
    acc.w += __shfl_down(acc.w, 32, 64);
    if (half == 0) {
        float sc = 1.0f + epsPtr[0];
        ushort4 xv = xh4[(size_t)node * 32 + q];
        acc.x = fmaf(sc, b2f(xv.x), acc.x);
        acc.y = fmaf(sc, b2f(xv.y), acc.y);
        acc.z = fmaf(sc, b2f(xv.z), acc.z);
        acc.w = fmaf(sc, b2f(xv.w), acc.w);
        ushort4 o;
        o.x = f2b(acc.x); o.y = f2b(acc.y); o.z = f2b(acc.z); o.w = f2b(acc.w);
        ((ushort4*)h0h)[(size_t)node * 32 + q] = o;
    }
}

// ---------- K5: MFMA GEMM1: h1 = h0h @ W1^T + b1 (bf16 in, fp32 acc) + BN stats ----------
// Block = 4 waves, 64 rows. Wave: 16 rows; 8 n-tiles x 4 k-steps of mfma 16x16x32.
// A[m=lane&15][k=q*8+j] from global; B[n=lane&15][k=q*8+j] from LDS (W row-major).
// D: col=lane&15 (in n-tile), row=q*4+reg.
#define WLD 136   // padded LDS row stride (elements)
__global__ __launch_bounds__(256, 2) void gemm1_mfma_kernel(const unsigned short* __restrict__ h0h,
                                                            const unsigned short* __restrict__ w1h,
                                                            const float* __restrict__ b1,
                                                            unsigned short* __restrict__ h1h,
                                                            float* __restrict__ stats, int n) {
    __shared__ unsigned short wl[128 * WLD];
    __shared__ float red[4 * 256];
    int tid = threadIdx.x;
    for (int i = tid; i < 128 * 16; i += 256) {
        int r = i >> 4, ch = i & 15;
        *(short8*)(wl + r * WLD + ch * 8) = *(const short8*)(w1h + r * 128 + ch * 8);
    }
    __syncthreads();

    int wv = tid >> 6, lane = tid & 63;
    int q = lane >> 4, c15 = lane & 15;
    int rowbase = blockIdx.x * 64 + wv * 16;
    int arow = rowbase + c15; if (arow >= n) arow = n - 1;
    const unsigned short* aptr = h0h + (size_t)arow * 128 + q * 8;

    float4v acc[8];
#pragma unroll
    for (int nt = 0; nt < 8; nt++) {
        float bb = b1[nt * 16 + c15];
        acc[nt] = (float4v){bb, bb, bb, bb};
    }
#pragma unroll
    for (int ks = 0; ks < 4; ks++) {
        short8 a = *(const short8*)(aptr + ks * 32);
        const unsigned short* wp = wl + q * 8 + ks * 32;
#pragma unroll
        for (int nt = 0; nt < 8; nt++) {
            short8 b = *(const short8*)(wp + (nt * 16 + c15) * WLD);
            acc[nt] = __builtin_amdgcn_mfma_f32_16x16x32_bf16(a, b, acc[nt], 0, 0, 0);
        }
    }

    // epilogue: store h1h (bf16) + per-col stats
    float sum[8], sq[8];
#pragma unroll
    for (int nt = 0; nt < 8; nt++) {
        sum[nt] = 0.f; sq[nt] = 0.f;
#pragma unroll
        for (int r = 0; r < 4; r++) {
            int row = rowbase + q * 4 + r;
            if (row < n) {
                float v = acc[nt][r];
                h1h[(size_t)row * 128 + nt * 16 + c15] = f2b(v);
                sum[nt] += v; sq[nt] += v * v;
            }
        }
        sum[nt] += __shfl_xor(sum[nt], 16, 64);
        sum[nt] += __shfl_xor(sum[nt], 32, 64);
        sq[nt]  += __shfl_xor(sq[nt], 16, 64);
        sq[nt]  += __shfl_xor(sq[nt], 32, 64);
    }
    if (lane < 16) {
#pragma unroll
        for (int nt = 0; nt < 8; nt++) {
            red[wv * 256 + nt * 16 + c15] = sum[nt];
            red[wv * 256 + 128 + nt * 16 + c15] = sq[nt];
        }
    }
    __syncthreads();
    if (wv == 0) {
        for (int c = lane; c < 128; c += 64) {
            float S = red[c] + red[256 + c] + red[512 + c] + red[768 + c];
            float Q = red[128 + c] + red[384 + c] + red[640 + c] + red[896 + c];
            atomicAdd(&stats[c], S);
            atomicAdd(&stats[128 + c], Q);
        }
    }
}

// ---------- K6: finalize BN -> scale/shift ----------
__global__ void bn_finalize_kernel(const float* __restrict__ stats, const float* __restrict__ gamma,
                                   const float* __restrict__ beta, float* __restrict__ ss, int n) {
    int c = threadIdx.x;
    float inv_n = 1.0f / (float)n;
    float mu = stats[c] * inv_n;
    float var = stats[F + c] * inv_n - mu * mu;
    var = fmaxf(var, 0.0f);
    float rs = rsqrtf(var + 1e-5f);
    float s = gamma[c] * rs;
    ss[c] = s;
    ss[F + c] = beta[c] - mu * s;
}

// ---------- K7: MFMA GEMM2: out = relu(BN(h1h)) @ W2^T + b2, fp32 out ----------
__global__ __launch_bounds__(256, 2) void gemm2_mfma_kernel(const unsigned short* __restrict__ h1h,
                                                            const unsigned short* __restrict__ w2h,
                                                            const float* __restrict__ b2,
                                                            const float* __restrict__ ss,
                                                            float* __restrict__ out, int n) {
    __shared__ unsigned short wl[128 * WLD];
    int tid = threadIdx.x;
    for (int i = tid; i < 128 * 16; i += 256) {
        int r = i >> 4, ch = i & 15;
        *(short8*)(wl + r * WLD + ch * 8) = *(const short8*)(w2h + r * 128 + ch * 8);
    }
    __syncthreads();

    int wv = tid >> 6, lane = tid & 63;
    int q = lane >> 4, c15 = lane & 15;
    int rowbase = blockIdx.x * 64 + wv * 16;
    int arow = rowbase + c15; if (arow >= n) arow = n - 1;
    const unsigned short* aptr = h1h + (size_t)arow * 128 + q * 8;

    float4v acc[8];
#pragma unroll
    for (int nt = 0; nt < 8; nt++) {
        float bb = b2[nt * 16 + c15];
        acc[nt] = (float4v){bb, bb, bb, bb};
    }
#pragma unroll
    for (int ks = 0; ks < 4; ks++) {
        short8 araw = *(const short8*)(aptr + ks * 32);
        const float* ssp = ss + ks * 32 + q * 8;
        float4 s0 = *(const float4*)(ssp);
        float4 s1 = *(const float4*)(ssp + 4);
        float4 t0 = *(const float4*)(ssp + 128);
        float4 t1 = *(const float4*)(ssp + 132);
        short8 a;
        a[0] = (short)f2b(fmaxf(fmaf(b2f((unsigned short)araw[0]), s0.x, t0.x), 0.f));
        a[1] = (short)f2b(fmaxf(fmaf(b2f((unsigned short)araw[1]), s0.y, t0.y), 0.f));
        a[2] = (short)f2b(fmaxf(fmaf(b2f((unsigned short)araw[2]), s0.z, t0.z), 0.f));
        a[3] = (short)f2b(fmaxf(fmaf(b2f((unsigned short)araw[3]), s0.w, t0.w), 0.f));
        a[4] = (short)f2b(fmaxf(fmaf(b2f((unsigned short)araw[4]), s1.x, t1.x), 0.f));
        a[5] = (short)f2b(fmaxf(fmaf(b2f((unsigned short)araw[5]), s1.y, t1.y), 0.f));
        a[6] = (short)f2b(fmaxf(fmaf(b2f((unsigned short)araw[6]), s1.z, t1.z), 0.f));
        a[7] = (short)f2b(fmaxf(fmaf(b2f((unsigned short)araw[7]), s1.w, t1.w), 0.f));
        const unsigned short* wp = wl + q * 8 + ks * 32;
#pragma unroll
        for (int nt = 0; nt < 8; nt++) {
            short8 b = *(const short8*)(wp + (nt * 16 + c15) * WLD);
            acc[nt] = __builtin_amdgcn_mfma_f32_16x16x32_bf16(a, b, acc[nt], 0, 0, 0);
        }
    }
#pragma unroll
    for (int nt = 0; nt < 8; nt++) {
#pragma unroll
        for (int r = 0; r < 4; r++) {
            int row = rowbase + q * 4 + r;
            if (row < n)
                out[(size_t)row * 128 + nt * 16 + c15] = acc[nt][r];
        }
    }
}

extern "C" void kernel_launch(void* const* d_in, const int* in_sizes, int n_in,
                              void* d_out, int out_size, void* d_ws, size_t ws_size,
                              hipStream_t stream) {
    const float* x     = (const float*)d_in[0];
    const int*   ei    = (const int*)d_in[1];
    const float* eps   = (const float*)d_in[2];
    const float* W1    = (const float*)d_in[3];
    const float* b1    = (const float*)d_in[4];
    const float* gamma = (const float*)d_in[5];
    const float* beta  = (const float*)d_in[6];
    const float* W2    = (const float*)d_in[7];
    const float* b2    = (const float*)d_in[8];
    float* out = (float*)d_out;

    const int E = in_sizes[1] / 2;
    const int n = in_sizes[0] / F;
    const int nbuk = (n + NPB - 1) / NPB;   // 1563

    char* w = (char*)d_ws;
    auto alloc = [&](size_t bytes) -> void* {
        void* p = (void*)w;
        w += (bytes + 255) & ~(size_t)255;
        return p;
    };
    int*            bucketCnt = (int*)alloc((size_t)nbuk * 4);
    int*            bOffs     = (int*)alloc((size_t)(nbuk + 1) * 4);
    int*            gcursor   = (int*)alloc((size_t)nbuk * 4);
    int*            offs      = (int*)alloc((size_t)(n + 1) * 4);
    float*          stats     = (float*)alloc(256 * 4);
    float*          ss        = (float*)alloc(256 * 4);
    unsigned short* w1h       = (unsigned short*)alloc(F * F * 2);
    unsigned short* w2h       = (unsigned short*)alloc(F * F * 2);
    int*            recbuf    = (int*)alloc((size_t)E * 4);
    int*            clist     = (int*)alloc((size_t)E * 4);
    unsigned short* xh        = (unsigned short*)alloc((size_t)n * F * 2);
    unsigned short* h0h       = (unsigned short*)alloc((size_t)n * F * 2);
    unsigned short* h1h       = (unsigned short*)alloc((size_t)n * F * 2);

    const int* rows = ei;
    const int* cols = ei + E;

    hipMemsetAsync(bucketCnt, 0, (size_t)nbuk * 4, stream);
    hipMemsetAsync(stats, 0, 256 * 4, stream);

    conv_x_kernel<<<(n * F / 8 + 255) / 256, 256, 0, stream>>>(x, xh, n * F);
    conv_w_kernel<<<64, 256, 0, stream>>>(W1, W2, w1h, w2h);
    bucket_hist_kernel<<<256, 256, nbuk * 4, stream>>>(rows, bucketCnt, E, nbuk);
    scan_buckets_kernel<<<1, 256, 0, stream>>>(bucketCnt, bOffs, gcursor, nbuk);
    binned_scatter_kernel<<<128, 1024, nbuk * 8, stream>>>(rows, cols, gcursor, recbuf, E, nbuk);
    bucket_sort_kernel<<<nbuk, 256, 0, stream>>>(recbuf, bOffs, clist, offs, n, nbuk);
    agg_kernel<<<(n + 3) / 4, 256, 0, stream>>>(xh, offs, clist, eps, h0h, n);

    int ntiles = (n + 63) / 64;
    gemm1_mfma_kernel<<<ntiles, 256, 0, stream>>>(h0h, w1h, b1, h1h, stats, n);
    bn_finalize_kernel<<<1, 128, 0, stream>>>(stats, gamma, beta, ss, n);
    gemm2_mfma_kernel<<<ntiles, 256, 0, stream>>>(h1h, w2h, b2, ss, out, n);
}